// Round 1
// 571.770 us; speedup vs baseline: 1.0051x; 1.0051x over previous
//
#include <hip/hip_runtime.h>
#include <cstddef>
#include <cstdint>

// Problem constants
constexpr int Bz = 8, CIN = 256, Hh = 96, Ww = 96;
constexpr int EMB1 = 256, EMB2 = 128, NCLS = 80;
constexpr int HP = 98; // padded spatial
constexpr size_t PIX = (size_t)Hh * Ww;                 // 9216
constexpr size_t XP_ELEMS = (size_t)Bz * HP * HP * CIN; // 19,668,992 bf16 elems

// Output layout (flat concat, fp32)
constexpr size_t O0 = 0;                       // cls_score      (B,80,96,96)
constexpr size_t O1 = (size_t)Bz * NCLS * PIX; // cls_score_neg
constexpr size_t O2 = 2 * O1;                  // distances
constexpr size_t O3 = 3 * O1;                  // distances_neg  (B,80,3,96,96)
constexpr size_t O4 = 6 * O1;                  // probs_ori

typedef short bf16x8 __attribute__((ext_vector_type(8)));
typedef float f32x4 __attribute__((ext_vector_type(4)));

__device__ inline unsigned short f2bf(float f) {
  union { float f; unsigned int u; } v; v.f = f;
  unsigned int r = v.u + 0x7fffu + ((v.u >> 16) & 1u);
  return (unsigned short)(r >> 16);
}

// async global->LDS, 16B per lane; LDS dest = wave-uniform base + lane*16
#define GLD16(gp, lp)                                              \
  __builtin_amdgcn_global_load_lds(                                \
      (__attribute__((address_space(1))) void*)((void*)(gp)),      \
      (__attribute__((address_space(3))) void*)(lp), 16, 0, 0)

// ---------------------------------------------------------------------------
// Prep: x (NCHW fp32) -> padded NHWC bf16 interior (borders via memset).
// LDS transpose: coalesced 128B reads per half-wave, conflict-free LDS,
// coalesced bf16 row writes. Tile = 32 px (one row segment) x 256 ch.
__global__ __launch_bounds__(256) void pad_x_kernel(const float* __restrict__ x,
                                                    unsigned short* __restrict__ xp) {
  __shared__ float tile[32][257];
  const int b = blockIdx.z, y = blockIdx.y, x0 = blockIdx.x * 32;
  const int t = threadIdx.x;
  const int px = t & 31, cg = t >> 5;  // 8 channel groups
  const float* src = x + (((size_t)b * CIN) * Hh + y) * Ww + x0 + px;
#pragma unroll 4
  for (int c = cg; c < CIN; c += 8)
    tile[px][c] = src[(size_t)c * Hh * Ww];
  __syncthreads();
  unsigned short* orow =
      xp + (((size_t)b * HP + y + 1) * HP + (x0 + 1)) * 256 + t;
#pragma unroll 4
  for (int p = 0; p < 32; ++p)
    orow[(size_t)p * 256] = f2bf(tile[p][t]);
}

// Prep: weights -> bf16 [tap][oc][ic]; BN fold (fp32 scale/offset)
__global__ __launch_bounds__(256) void prep_w_kernel(
    const float* __restrict__ w1, const float* __restrict__ w2,
    const float* __restrict__ c1b, const float* __restrict__ g,
    const float* __restrict__ be, const float* __restrict__ mu,
    const float* __restrict__ var, unsigned short* __restrict__ wt1,
    unsigned short* __restrict__ wt2, float* __restrict__ bns,
    float* __restrict__ bno) {
  const int idx = blockIdx.x * 256 + threadIdx.x;
  if (idx < 9 * 256 * 256) {  // wt1[tap][oc][ic]
    const int ic = idx & 255, oc = (idx >> 8) & 255, tap = idx >> 16;
    wt1[idx] = f2bf(w1[((size_t)(oc * 256 + ic)) * 9 + tap]);
  }
  if (idx < 9 * 128 * 256) {  // wt2[tap][oc][ic]
    const int ic = idx & 255, oc = (idx >> 8) & 127, tap = idx >> 15;
    wt2[idx] = f2bf(w2[((size_t)(oc * 256 + ic)) * 9 + tap]);
  }
  if (idx < 256) {
    const float s = g[idx] * rsqrtf(var[idx] + 1e-5f);
    bns[idx] = s;
    bno[idx] = (c1b[idx] - mu[idx]) * s + be[idx];
  }
}

// reps = l2norm(rep_w[:,0] + rep_b) per class (80 x 128); fp32 rpv + bf16 Rb
__global__ __launch_bounds__(128) void rep_norm_kernel(const float* __restrict__ rw,
                                                       const float* __restrict__ rb,
                                                       float* __restrict__ r,
                                                       unsigned short* __restrict__ Rb) {
  __shared__ float red[2];
  const int c = blockIdx.x, t = threadIdx.x;
  const float v = rw[c * 128 + t] + rb[c * 128 + t];
  float s = v * v;
  for (int msk = 1; msk < 64; msk <<= 1) s += __shfl_xor(s, msk, 64);
  if ((t & 63) == 0) red[t >> 6] = s;
  __syncthreads();
  const float ss = red[0] + red[1];
  const float rn = 1.f / fmaxf(sqrtf(ss), 1e-12f);
  r[c * 128 + t] = v * rn;
  Rb[(size_t)(c * 4) * 128 + t] = f2bf(v * rn);  // rep slot v=0 (positive)
}

// reps_neg: per (class, neg) 3-layer MLP on r, then l2norm -> bf16 Rb slot
__global__ __launch_bounds__(128) void mlp_neg_kernel(const float* __restrict__ r,
                                                      const float* __restrict__ W,
                                                      const float* __restrict__ bb,
                                                      unsigned short* __restrict__ Rb) {
  __shared__ float h0[128], h1[128];
  __shared__ float red[2];
  const int c = blockIdx.x, ng = blockIdx.y, t = threadIdx.x;
  h0[t] = r[c * 128 + t];
  __syncthreads();
  float s = 0.f;
  for (int lay = 0; lay < 3; ++lay) {
    const float* hin = (lay & 1) ? h1 : h0;
    float* hout = (lay & 1) ? h0 : h1;
    const float* wr = W + (((size_t)ng * 3 + lay) * 128 + t) * 128;
    s = bb[(ng * 3 + lay) * 128 + t];
    for (int e = 0; e < 128; ++e) s += wr[e] * hin[e];
    if (lay < 2) hout[t] = fmaxf(s, 0.f);
    __syncthreads();
  }
  float q = s * s;
  for (int msk = 1; msk < 64; msk <<= 1) q += __shfl_xor(q, msk, 64);
  if ((t & 63) == 0) red[t >> 6] = q;
  __syncthreads();
  const float ss = red[0] + red[1];
  const float rn = 1.f / fmaxf(sqrtf(ss), 1e-12f);
  Rb[((size_t)(c * 4) + 1 + ng) * 128 + t] = f2bf(s * rn);
}

// ---------------------------------------------------------------------------
// bf16 MFMA implicit-GEMM 3x3 conv, NHWC (padded input HPxHP, IC=256).
// Block tile: 128 px (8 rows x 16 cols) x 128 oc. BK=32. 4 waves, each 64x64
// via 4x4 grid of mfma_f32_16x16x32_bf16. global_load_lds width-16 staging.
// 2-phase double-buffered pipeline (T3-minimum): prefetch step s+1 into
// buf^1 before computing step s; ONE __syncthreads() per step (vmcnt drain
// lands AFTER the MFMAs, so stage latency is hidden under compute).
// BN=true: out bf16 padded NHWC (B,98,98,256) at (y+1,x+1), v=acc*e0+e1
// BN=false: out bf16 NHWC (B,96,96,128), v=l2norm_c(acc+e0) (fused l2norm)
template <int OC, bool BN>
__global__ __launch_bounds__(256) void conv3x3_mfma(
    const unsigned short* __restrict__ in, const unsigned short* __restrict__ wt,
    const float* __restrict__ e0, const float* __restrict__ e1,
    unsigned short* __restrict__ out16) {
  __shared__ unsigned short smA[2][128 * 32];  // [buf][px][k] 64B rows
  __shared__ unsigned short smB[2][128 * 32];  // [buf][oc][k]
  __shared__ float nrm[128][2];                // fused l2norm partials (BN=false)
  const int tile = blockIdx.x;                 // 0..71
  const int oc0 = blockIdx.y * 128;
  const int b = blockIdx.z;
  const int ty = (tile / 6) * 8, tx = (tile % 6) * 16;
  const int t = threadIdx.x;
  const int lane = t & 63, w = t >> 6;
  const int wm = w & 1, wn = w >> 1;
  const int quad = lane >> 4, col = lane & 15;
  const int chl = (lane & 3) * 8;              // staging channel sub-offset

  // per-lane staging bases (tap/ch offsets are uniform, added per step)
  size_t baseA[2], baseB[2];
#pragma unroll
  for (int i = 0; i < 2; ++i) {
    const int px = (w * 2 + i) * 16 + (lane >> 2);
    const int rowA = ty + (px >> 4);
    const int colA = tx + (px & 15);
    const int ocB = oc0 + (w * 2 + i) * 16 + (lane >> 2);
    baseA[i] = (((size_t)b * HP + rowA) * HP + colA) * 256 + chl;
    baseB[i] = (size_t)ocB * 256 + chl;
  }

  f32x4 acc[4][4];
#pragma unroll
  for (int mt = 0; mt < 4; ++mt)
#pragma unroll
    for (int nt = 0; nt < 4; ++nt) acc[mt][nt] = {0.f, 0.f, 0.f, 0.f};

  // stage step s (s in [0,72)) into buffer buf
  auto stage = [&](int s, int buf) {
    const int tap = s >> 3;                // 0..8
    const int ch0 = (s & 7) << 5;          // 0..224
    const int sA = ((tap / 3) * HP + (tap % 3)) * 256 + ch0;  // uniform
    const int sB = tap * (OC * 256) + ch0;                    // uniform
    char* dA = (char*)smA[buf];
    char* dB = (char*)smB[buf];
    GLD16(in + baseA[0] + sA, dA + (w * 2 + 0) * 1024);
    GLD16(in + baseA[1] + sA, dA + (w * 2 + 1) * 1024);
    GLD16(wt + baseB[0] + sB, dB + (w * 2 + 0) * 1024);
    GLD16(wt + baseB[1] + sB, dB + (w * 2 + 1) * 1024);
  };

  stage(0, 0);
  __syncthreads();  // buf0 staged (vmcnt(0)+lgkmcnt drain for all waves)
  int cur = 0;
  for (int s = 0; s < 72; ++s) {
    if (s < 71) stage(s + 1, cur ^ 1);  // prefetch next step
    bf16x8 af[4], bf[4];
#pragma unroll
    for (int mt = 0; mt < 4; ++mt)
      af[mt] = *(const bf16x8*)((const char*)smA[cur] +
                                (wm * 64 + mt * 16 + col) * 64 + quad * 16);
#pragma unroll
    for (int nt = 0; nt < 4; ++nt)
      bf[nt] = *(const bf16x8*)((const char*)smB[cur] +
                                (wn * 64 + nt * 16 + col) * 64 + quad * 16);
#pragma unroll
    for (int mt = 0; mt < 4; ++mt)
#pragma unroll
      for (int nt = 0; nt < 4; ++nt)
        acc[mt][nt] = __builtin_amdgcn_mfma_f32_16x16x32_bf16(
            af[mt], bf[nt], acc[mt][nt], 0, 0, 0);
    __syncthreads();  // waits prefetch (after MFMA) + protects buf reuse
    cur ^= 1;
  }

  // epilogue
  float sc[4], of[4];
#pragma unroll
  for (int nt = 0; nt < 4; ++nt) {
    const int oc = oc0 + wn * 64 + nt * 16 + col;
    sc[nt] = e0[oc];
    of[nt] = BN ? e1[oc] : 0.f;
  }
  if (BN) {
#pragma unroll
    for (int mt = 0; mt < 4; ++mt)
#pragma unroll
      for (int r = 0; r < 4; ++r) {
        const int px = wm * 64 + mt * 16 + quad * 4 + r;
        const int y = ty + (px >> 4), x = tx + (px & 15);
        unsigned short* rowp =
            out16 + (((size_t)b * HP + y + 1) * HP + x + 1) * 256 + oc0 + wn * 64 + col;
#pragma unroll
        for (int nt = 0; nt < 4; ++nt)
          rowp[nt * 16] = f2bf(acc[mt][nt][r] * sc[nt] + of[nt]);
      }
  } else {
    // fused channel l2norm: this block owns ALL 128 output channels per px
    float part[4][4];
#pragma unroll
    for (int mt = 0; mt < 4; ++mt)
#pragma unroll
      for (int r = 0; r < 4; ++r) {
        float s = 0.f;
#pragma unroll
        for (int nt = 0; nt < 4; ++nt) {
          const float v = acc[mt][nt][r] + sc[nt];
          s += v * v;
        }
        part[mt][r] = s;
      }
#pragma unroll
    for (int msk = 1; msk < 16; msk <<= 1)
#pragma unroll
      for (int mt = 0; mt < 4; ++mt)
#pragma unroll
        for (int r = 0; r < 4; ++r)
          part[mt][r] += __shfl_xor(part[mt][r], msk, 64);
    if (col == 0) {
#pragma unroll
      for (int mt = 0; mt < 4; ++mt)
#pragma unroll
        for (int r = 0; r < 4; ++r)
          nrm[wm * 64 + mt * 16 + quad * 4 + r][wn] = part[mt][r];
    }
    __syncthreads();
#pragma unroll
    for (int mt = 0; mt < 4; ++mt)
#pragma unroll
      for (int r = 0; r < 4; ++r) {
        const int px = wm * 64 + mt * 16 + quad * 4 + r;
        const int y = ty + (px >> 4), x = tx + (px & 15);
        const float nn = nrm[px][0] + nrm[px][1];
        const float rn = 1.f / fmaxf(sqrtf(nn), 1e-12f);
        unsigned short* rowp =
            out16 + (((size_t)b * Hh + y) * Ww + x) * 128 + wn * 64 + col;
#pragma unroll
        for (int nt = 0; nt < 4; ++nt)
          rowp[nt * 16] = f2bf((acc[mt][nt][r] + sc[nt]) * rn);
      }
  }
}

// ---------------------------------------------------------------------------
// 4x4 transpose across lanes differing in bits 0..1 (regs r0..r3)
__device__ inline void xpose4(float& r0, float& r1, float& r2, float& r3,
                              int lane) {
  const int b1 = (lane >> 1) & 1, b0 = lane & 1;
  float s0 = b1 ? r0 : r2;
  float s1 = b1 ? r1 : r3;
  s0 = __shfl_xor(s0, 2, 64);
  s1 = __shfl_xor(s1, 2, 64);
  if (b1) { r0 = s0; r1 = s1; } else { r2 = s0; r3 = s1; }
  float t0 = b0 ? r0 : r1;
  float t1 = b0 ? r2 : r3;
  t0 = __shfl_xor(t0, 1, 64);
  t1 = __shfl_xor(t1, 1, 64);
  if (b0) { r0 = t0; r2 = t1; } else { r1 = t0; r3 = t1; }
}

// Score: MFMA GEMM (64 px x 320 reps, K=128) + fused epilogue, no LDS.
// Rep order: n = cls*4 + {pos, neg0, neg1, neg2}. Wave w covers n in
// [w*80, w*80+80) as 5 n-tiles of 16.
__global__ __launch_bounds__(256) void score_mfma(
    const unsigned short* __restrict__ embb, const unsigned short* __restrict__ Rb,
    float* __restrict__ out) {
  const int px0 = blockIdx.x * 64;
  const int b = blockIdx.y;
  const int t = threadIdx.x;
  const int lane = t & 63, w = t >> 6;
  const int quad = lane >> 4, col = lane & 15;
  const int n0 = w * 80;
  const unsigned short* Abase = embb + ((size_t)b * PIX + px0) * 128;

  f32x4 acc[4][5];
#pragma unroll
  for (int mt = 0; mt < 4; ++mt)
#pragma unroll
    for (int nt = 0; nt < 5; ++nt) acc[mt][nt] = {0.f, 0.f, 0.f, 0.f};

#pragma unroll
  for (int ks = 0; ks < 4; ++ks) {
    bf16x8 bf[5], af[4];
#pragma unroll
    for (int nt = 0; nt < 5; ++nt)
      bf[nt] = *(const bf16x8*)(Rb + (size_t)(n0 + nt * 16 + col) * 128 +
                                ks * 32 + quad * 8);
#pragma unroll
    for (int mt = 0; mt < 4; ++mt)
      af[mt] = *(const bf16x8*)(Abase + (size_t)(mt * 16 + col) * 128 +
                                ks * 32 + quad * 8);
#pragma unroll
    for (int mt = 0; mt < 4; ++mt)
#pragma unroll
      for (int nt = 0; nt < 5; ++nt)
        acc[mt][nt] = __builtin_amdgcn_mfma_f32_16x16x32_bf16(
            af[mt], bf[nt], acc[mt][nt], 0, 0, 0);
  }

  const int j = lane & 3, kq = (lane >> 2) & 3;
#pragma unroll
  for (int mt = 0; mt < 4; ++mt) {
    const int px = px0 + mt * 16 + quad * 4 + j;
#pragma unroll
    for (int nt = 0; nt < 5; ++nt) {
      float v0 = acc[mt][nt][0], v1 = acc[mt][nt][1];
      float v2 = acc[mt][nt][2], v3 = acc[mt][nt][3];
      xpose4(v0, v1, v2, v3, lane);
      // lane now holds (dp, dn0, dn1, dn2) for (px, cls)
      const int gc = w * 20 + nt * 4 + kq;
      const float d2p = fmaxf(2.f - 2.f * v0, 0.f);
      const float dist = sqrtf(d2p);
      const float q0 = fmaxf(2.f - 2.f * v1, 0.f);
      const float q1 = fmaxf(2.f - 2.f * v2, 0.f);
      const float q2 = fmaxf(2.f - 2.f * v3, 0.f);
      const float dn0 = sqrtf(q0), dn1 = sqrtf(q1), dn2 = sqrtf(q2);
      const float pn = __expf(-2.f * fminf(q0, fminf(q1, q2)));
      const float pori = __expf(-2.f * d2p);
      const float minn = fminf(dn0, fminf(dn1, dn2));
      const float shifted = dist + 0.3f * fmaxf(2.0f - minn, 0.f);
      const float p = __expf(-2.f * shifted * shifted);
      const float clsv = __logf(fmaxf(p, 1e-5f) / fmaxf(1.f - p, 1e-5f));
      const size_t bc = ((size_t)b * NCLS + gc) * PIX + px;
      out[O0 + bc] = clsv;
      out[O1 + bc] = pn;
      out[O2 + bc] = dist;
      out[O4 + bc] = pori;
      const size_t b3 = (((size_t)b * NCLS + gc) * 3) * PIX + px;
      out[O3 + b3] = dn0;
      out[O3 + b3 + PIX] = dn1;
      out[O3 + b3 + 2 * PIX] = dn2;
    }
  }
}

// ---------------------------------------------------------------------------
extern "C" void kernel_launch(void* const* d_in, const int* in_sizes, int n_in,
                              void* d_out, int out_size, void* d_ws,
                              size_t ws_size, hipStream_t stream) {
  const float* x = (const float*)d_in[0];
  const float* w1 = (const float*)d_in[1];
  const float* c1b = (const float*)d_in[2];
  const float* g = (const float*)d_in[3];
  const float* be = (const float*)d_in[4];
  const float* mu = (const float*)d_in[5];
  const float* var = (const float*)d_in[6];
  const float* w2 = (const float*)d_in[7];
  const float* c2b = (const float*)d_in[8];
  const float* rw = (const float*)d_in[9];
  const float* rb = (const float*)d_in[10];
  const float* nw = (const float*)d_in[11];
  const float* nb = (const float*)d_in[12];
  float* out = (float*)d_out;

  unsigned short* xp = (unsigned short*)d_ws;   // bf16 padded NHWC input
  unsigned short* hp = xp + XP_ELEMS;           // bf16 padded NHWC hidden
  unsigned short* wt1 = hp + XP_ELEMS;          // 589,824 bf16
  unsigned short* wt2 = wt1 + 589824;           // 294,912 bf16
  float* bns = (float*)(wt2 + 294912);
  float* bno = bns + 256;
  float* rpv = bno + 256;                       // 10,240 fp32
  unsigned short* Rb = (unsigned short*)(rpv + 10240);  // 40,960 bf16
  unsigned short* embb = xp;                    // alias: xp dead after conv1

  hipMemsetAsync(xp, 0, XP_ELEMS * sizeof(unsigned short), stream);
  hipMemsetAsync(hp, 0, XP_ELEMS * sizeof(unsigned short), stream);
  pad_x_kernel<<<dim3(3, Hh, Bz), 256, 0, stream>>>(x, xp);
  prep_w_kernel<<<2304, 256, 0, stream>>>(w1, w2, c1b, g, be, mu, var, wt1, wt2,
                                          bns, bno);
  rep_norm_kernel<<<NCLS, 128, 0, stream>>>(rw, rb, rpv, Rb);
  mlp_neg_kernel<<<dim3(NCLS, 3), 128, 0, stream>>>(rpv, nw, nb, Rb);
  conv3x3_mfma<256, true><<<dim3(72, 2, Bz), 256, 0, stream>>>(xp, wt1, bns,
                                                               bno, hp);
  conv3x3_mfma<128, false><<<dim3(72, 1, Bz), 256, 0, stream>>>(hp, wt2, c2b,
                                                                nullptr, embb);
  score_mfma<<<dim3(144, Bz), 256, 0, stream>>>(embb, Rb, out);
}

// Round 2
// 564.607 us; speedup vs baseline: 1.0179x; 1.0127x over previous
//
#include <hip/hip_runtime.h>
#include <cstddef>
#include <cstdint>

// Problem constants
constexpr int Bz = 8, CIN = 256, Hh = 96, Ww = 96;
constexpr int EMB1 = 256, EMB2 = 128, NCLS = 80;
constexpr int HP = 98; // padded spatial
constexpr size_t PIX = (size_t)Hh * Ww;                 // 9216
constexpr size_t XP_ELEMS = (size_t)Bz * HP * HP * CIN; // 19,668,992 bf16 elems

// Output layout (flat concat, fp32)
constexpr size_t O0 = 0;                       // cls_score      (B,80,96,96)
constexpr size_t O1 = (size_t)Bz * NCLS * PIX; // cls_score_neg
constexpr size_t O2 = 2 * O1;                  // distances
constexpr size_t O3 = 3 * O1;                  // distances_neg  (B,80,3,96,96)
constexpr size_t O4 = 6 * O1;                  // probs_ori

typedef short bf16x8 __attribute__((ext_vector_type(8)));
typedef float f32x4 __attribute__((ext_vector_type(4)));

__device__ inline unsigned short f2bf(float f) {
  union { float f; unsigned int u; } v; v.f = f;
  unsigned int r = v.u + 0x7fffu + ((v.u >> 16) & 1u);
  return (unsigned short)(r >> 16);
}

// async global->LDS, 16B per lane; LDS dest = wave-uniform base + lane*16
#define GLD16(gp, lp)                                              \
  __builtin_amdgcn_global_load_lds(                                \
      (__attribute__((address_space(1))) void*)((void*)(gp)),      \
      (__attribute__((address_space(3))) void*)(lp), 16, 0, 0)

// ---------------------------------------------------------------------------
// Prep: x (NCHW fp32) -> padded NHWC bf16 interior (borders via memset).
// LDS transpose: coalesced 128B reads per half-wave, conflict-free LDS,
// coalesced bf16 row writes. Tile = 32 px (one row segment) x 256 ch.
__global__ __launch_bounds__(256) void pad_x_kernel(const float* __restrict__ x,
                                                    unsigned short* __restrict__ xp) {
  __shared__ float tile[32][257];
  const int b = blockIdx.z, y = blockIdx.y, x0 = blockIdx.x * 32;
  const int t = threadIdx.x;
  const int px = t & 31, cg = t >> 5;  // 8 channel groups
  const float* src = x + (((size_t)b * CIN) * Hh + y) * Ww + x0 + px;
#pragma unroll 4
  for (int c = cg; c < CIN; c += 8)
    tile[px][c] = src[(size_t)c * Hh * Ww];
  __syncthreads();
  unsigned short* orow =
      xp + (((size_t)b * HP + y + 1) * HP + (x0 + 1)) * 256 + t;
#pragma unroll 4
  for (int p = 0; p < 32; ++p)
    orow[(size_t)p * 256] = f2bf(tile[p][t]);
}

// Prep: weights -> bf16 [tap][oc][ic]; BN fold (fp32 scale/offset)
__global__ __launch_bounds__(256) void prep_w_kernel(
    const float* __restrict__ w1, const float* __restrict__ w2,
    const float* __restrict__ c1b, const float* __restrict__ g,
    const float* __restrict__ be, const float* __restrict__ mu,
    const float* __restrict__ var, unsigned short* __restrict__ wt1,
    unsigned short* __restrict__ wt2, float* __restrict__ bns,
    float* __restrict__ bno) {
  const int idx = blockIdx.x * 256 + threadIdx.x;
  if (idx < 9 * 256 * 256) {  // wt1[tap][oc][ic]
    const int ic = idx & 255, oc = (idx >> 8) & 255, tap = idx >> 16;
    wt1[idx] = f2bf(w1[((size_t)(oc * 256 + ic)) * 9 + tap]);
  }
  if (idx < 9 * 128 * 256) {  // wt2[tap][oc][ic]
    const int ic = idx & 255, oc = (idx >> 8) & 127, tap = idx >> 15;
    wt2[idx] = f2bf(w2[((size_t)(oc * 256 + ic)) * 9 + tap]);
  }
  if (idx < 256) {
    const float s = g[idx] * rsqrtf(var[idx] + 1e-5f);
    bns[idx] = s;
    bno[idx] = (c1b[idx] - mu[idx]) * s + be[idx];
  }
}

// reps = l2norm(rep_w[:,0] + rep_b) per class (80 x 128); fp32 rpv + bf16 Rb
__global__ __launch_bounds__(128) void rep_norm_kernel(const float* __restrict__ rw,
                                                       const float* __restrict__ rb,
                                                       float* __restrict__ r,
                                                       unsigned short* __restrict__ Rb) {
  __shared__ float red[2];
  const int c = blockIdx.x, t = threadIdx.x;
  const float v = rw[c * 128 + t] + rb[c * 128 + t];
  float s = v * v;
  for (int msk = 1; msk < 64; msk <<= 1) s += __shfl_xor(s, msk, 64);
  if ((t & 63) == 0) red[t >> 6] = s;
  __syncthreads();
  const float ss = red[0] + red[1];
  const float rn = 1.f / fmaxf(sqrtf(ss), 1e-12f);
  r[c * 128 + t] = v * rn;
  Rb[(size_t)(c * 4) * 128 + t] = f2bf(v * rn);  // rep slot v=0 (positive)
}

// reps_neg: per (class, neg) 3-layer MLP on r, then l2norm -> bf16 Rb slot
__global__ __launch_bounds__(128) void mlp_neg_kernel(const float* __restrict__ r,
                                                      const float* __restrict__ W,
                                                      const float* __restrict__ bb,
                                                      unsigned short* __restrict__ Rb) {
  __shared__ float h0[128], h1[128];
  __shared__ float red[2];
  const int c = blockIdx.x, ng = blockIdx.y, t = threadIdx.x;
  h0[t] = r[c * 128 + t];
  __syncthreads();
  float s = 0.f;
  for (int lay = 0; lay < 3; ++lay) {
    const float* hin = (lay & 1) ? h1 : h0;
    float* hout = (lay & 1) ? h0 : h1;
    const float* wr = W + (((size_t)ng * 3 + lay) * 128 + t) * 128;
    s = bb[(ng * 3 + lay) * 128 + t];
    for (int e = 0; e < 128; ++e) s += wr[e] * hin[e];
    if (lay < 2) hout[t] = fmaxf(s, 0.f);
    __syncthreads();
  }
  float q = s * s;
  for (int msk = 1; msk < 64; msk <<= 1) q += __shfl_xor(q, msk, 64);
  if ((t & 63) == 0) red[t >> 6] = q;
  __syncthreads();
  const float ss = red[0] + red[1];
  const float rn = 1.f / fmaxf(sqrtf(ss), 1e-12f);
  Rb[((size_t)(c * 4) + 1 + ng) * 128 + t] = f2bf(s * rn);
}

// ---------------------------------------------------------------------------
// bf16 MFMA implicit-GEMM 3x3 conv, NHWC (padded input HPxHP, IC=256).
// Block tile: 128 px (8 rows x 16 cols) x 128 oc. BK=32. 4 waves, each 64x64
// via 4x4 grid of mfma_f32_16x16x32_bf16. global_load_lds width-16 staging.
// Pipeline: nested tap loop (addresses hoisted, 9x), inner 4x-unrolled pair
// loop with COMPILE-TIME buffer indices; stage of step s+1 issued before
// compute of step s (16 MFMAs cover the load latency before the barrier's
// vmcnt drain); cross-tap prefetch via next-tap pointers. One barrier/step.
// BN=true: out bf16 padded NHWC (B,98,98,256) at (y+1,x+1), v=acc*e0+e1
// BN=false: out bf16 NHWC (B,96,96,128), v=l2norm_c(acc+e0) (fused l2norm)
template <int OC, bool BN>
__device__ __forceinline__ void conv3x3_body(
    const unsigned short* __restrict__ in, const unsigned short* __restrict__ wt,
    const float* __restrict__ e0, const float* __restrict__ e1,
    unsigned short* __restrict__ out16) {
  __shared__ unsigned short smA[2][128 * 32];  // [buf][px][k] 64B rows
  __shared__ unsigned short smB[2][128 * 32];  // [buf][oc][k]
  __shared__ float nrm[128][2];                // fused l2norm partials (BN=false)
  const int tile = blockIdx.x;                 // 0..71
  const int oc0 = blockIdx.y * 128;
  const int b = blockIdx.z;
  const int ty = (tile / 6) * 8, tx = (tile % 6) * 16;
  const int t = threadIdx.x;
  const int lane = t & 63, w = t >> 6;
  const int wm = w & 1, wn = w >> 1;
  const int quad = lane >> 4, col = lane & 15;
  const int chl = (lane & 3) * 8;              // staging channel sub-offset

  // tap-independent per-lane geometry
  int rowA[2], colA[2];
  size_t bB0[2];
#pragma unroll
  for (int i = 0; i < 2; ++i) {
    const int px = (w * 2 + i) * 16 + (lane >> 2);
    rowA[i] = ty + (px >> 4);
    colA[i] = tx + (px & 15);
    const int ocB = oc0 + (w * 2 + i) * 16 + (lane >> 2);
    bB0[i] = (size_t)ocB * 256 + chl;
  }

  f32x4 acc[4][4];
#pragma unroll
  for (int mt = 0; mt < 4; ++mt)
#pragma unroll
    for (int nt = 0; nt < 4; ++nt) acc[mt][nt] = {0.f, 0.f, 0.f, 0.f};

  auto mk = [&](int tap, const unsigned short*& A0, const unsigned short*& A1,
                const unsigned short*& B0, const unsigned short*& B1) {
    const int ky = tap / 3, kx = tap % 3;
    A0 = in + (((size_t)b * HP + rowA[0] + ky) * HP + colA[0] + kx) * 256 + chl;
    A1 = in + (((size_t)b * HP + rowA[1] + ky) * HP + colA[1] + kx) * 256 + chl;
    B0 = wt + (size_t)tap * (OC * 256) + bB0[0];
    B1 = wt + (size_t)tap * (OC * 256) + bB0[1];
  };
  auto stage = [&](const unsigned short* A0, const unsigned short* A1,
                   const unsigned short* B0, const unsigned short* B1,
                   int ch, int buf) {
    GLD16(A0 + ch, (char*)smA[buf] + (w * 2 + 0) * 1024);
    GLD16(A1 + ch, (char*)smA[buf] + (w * 2 + 1) * 1024);
    GLD16(B0 + ch, (char*)smB[buf] + (w * 2 + 0) * 1024);
    GLD16(B1 + ch, (char*)smB[buf] + (w * 2 + 1) * 1024);
  };
  auto compute = [&](int buf) {
    bf16x8 af[4], bf[4];
#pragma unroll
    for (int mt = 0; mt < 4; ++mt)
      af[mt] = *(const bf16x8*)((const char*)smA[buf] +
                                (wm * 64 + mt * 16 + col) * 64 + quad * 16);
#pragma unroll
    for (int nt = 0; nt < 4; ++nt)
      bf[nt] = *(const bf16x8*)((const char*)smB[buf] +
                                (wn * 64 + nt * 16 + col) * 64 + quad * 16);
#pragma unroll
    for (int mt = 0; mt < 4; ++mt)
#pragma unroll
      for (int nt = 0; nt < 4; ++nt)
        acc[mt][nt] = __builtin_amdgcn_mfma_f32_16x16x32_bf16(
            af[mt], bf[nt], acc[mt][nt], 0, 0, 0);
  };

  const unsigned short *a0, *a1, *b0, *b1;
  mk(0, a0, a1, b0, b1);
  const unsigned short *a0n = a0, *a1n = a1, *b0n = b0, *b1n = b1;
  stage(a0, a1, b0, b1, 0, 0);
  __syncthreads();  // buf0 of (tap0, ch0) staged

  for (int tap = 0; tap < 9; ++tap) {
    if (tap < 8) mk(tap + 1, a0n, a1n, b0n, b1n);
#pragma unroll
    for (int cp = 0; cp < 4; ++cp) {
      const int c0 = cp * 64;  // elements; two 32-ch steps per pair
      stage(a0, a1, b0, b1, c0 + 32, 1);   // prefetch odd step -> buf1
      compute(0);                          // compute even step from buf0
      __syncthreads();
      if (cp < 3)
        stage(a0, a1, b0, b1, c0 + 64, 0); // prefetch next even -> buf0
      else if (tap < 8)
        stage(a0n, a1n, b0n, b1n, 0, 0);   // cross-tap prefetch -> buf0
      compute(1);                          // compute odd step from buf1
      __syncthreads();
    }
    a0 = a0n; a1 = a1n; b0 = b0n; b1 = b1n;
  }

  // epilogue
  float sc[4], of[4];
#pragma unroll
  for (int nt = 0; nt < 4; ++nt) {
    const int oc = oc0 + wn * 64 + nt * 16 + col;
    sc[nt] = e0[oc];
    of[nt] = BN ? e1[oc] : 0.f;
  }
  if (BN) {
#pragma unroll
    for (int mt = 0; mt < 4; ++mt)
#pragma unroll
      for (int r = 0; r < 4; ++r) {
        const int px = wm * 64 + mt * 16 + quad * 4 + r;
        const int y = ty + (px >> 4), x = tx + (px & 15);
        unsigned short* rowp =
            out16 + (((size_t)b * HP + y + 1) * HP + x + 1) * 256 + oc0 + wn * 64 + col;
#pragma unroll
        for (int nt = 0; nt < 4; ++nt)
          rowp[nt * 16] = f2bf(acc[mt][nt][r] * sc[nt] + of[nt]);
      }
  } else {
    // fused channel l2norm: this block owns ALL 128 output channels per px
    float part[4][4];
#pragma unroll
    for (int mt = 0; mt < 4; ++mt)
#pragma unroll
      for (int r = 0; r < 4; ++r) {
        float s = 0.f;
#pragma unroll
        for (int nt = 0; nt < 4; ++nt) {
          const float v = acc[mt][nt][r] + sc[nt];
          s += v * v;
        }
        part[mt][r] = s;
      }
#pragma unroll
    for (int msk = 1; msk < 16; msk <<= 1)
#pragma unroll
      for (int mt = 0; mt < 4; ++mt)
#pragma unroll
        for (int r = 0; r < 4; ++r)
          part[mt][r] += __shfl_xor(part[mt][r], msk, 64);
    if (col == 0) {
#pragma unroll
      for (int mt = 0; mt < 4; ++mt)
#pragma unroll
        for (int r = 0; r < 4; ++r)
          nrm[wm * 64 + mt * 16 + quad * 4 + r][wn] = part[mt][r];
    }
    __syncthreads();
#pragma unroll
    for (int mt = 0; mt < 4; ++mt)
#pragma unroll
      for (int r = 0; r < 4; ++r) {
        const int px = wm * 64 + mt * 16 + quad * 4 + r;
        const int y = ty + (px >> 4), x = tx + (px & 15);
        const float nn = nrm[px][0] + nrm[px][1];
        const float rn = 1.f / fmaxf(sqrtf(nn), 1e-12f);
        unsigned short* rowp =
            out16 + (((size_t)b * Hh + y) * Ww + x) * 128 + wn * 64 + col;
#pragma unroll
        for (int nt = 0; nt < 4; ++nt)
          rowp[nt * 16] = f2bf((acc[mt][nt][r] + sc[nt]) * rn);
      }
  }
}

// distinct names so rocprof rows distinguish conv1 vs conv2
__global__ __launch_bounds__(256) void conv1_mfma(
    const unsigned short* __restrict__ in, const unsigned short* __restrict__ wt,
    const float* __restrict__ e0, const float* __restrict__ e1,
    unsigned short* __restrict__ out16) {
  conv3x3_body<256, true>(in, wt, e0, e1, out16);
}
__global__ __launch_bounds__(256) void conv2_mfma(
    const unsigned short* __restrict__ in, const unsigned short* __restrict__ wt,
    const float* __restrict__ e0, const float* __restrict__ e1,
    unsigned short* __restrict__ out16) {
  conv3x3_body<128, false>(in, wt, e0, e1, out16);
}

// ---------------------------------------------------------------------------
// 4x4 transpose across lanes differing in bits 0..1 (regs r0..r3)
__device__ inline void xpose4(float& r0, float& r1, float& r2, float& r3,
                              int lane) {
  const int b1 = (lane >> 1) & 1, b0 = lane & 1;
  float s0 = b1 ? r0 : r2;
  float s1 = b1 ? r1 : r3;
  s0 = __shfl_xor(s0, 2, 64);
  s1 = __shfl_xor(s1, 2, 64);
  if (b1) { r0 = s0; r1 = s1; } else { r2 = s0; r3 = s1; }
  float t0 = b0 ? r0 : r1;
  float t1 = b0 ? r2 : r3;
  t0 = __shfl_xor(t0, 1, 64);
  t1 = __shfl_xor(t1, 1, 64);
  if (b0) { r0 = t0; r2 = t1; } else { r1 = t0; r3 = t1; }
}

// Score: MFMA GEMM (64 px x 320 reps, K=128) + fused epilogue, no LDS.
// Rep order: n = cls*4 + {pos, neg0, neg1, neg2}. Wave w covers n in
// [w*80, w*80+80) as 5 n-tiles of 16.
__global__ __launch_bounds__(256) void score_mfma(
    const unsigned short* __restrict__ embb, const unsigned short* __restrict__ Rb,
    float* __restrict__ out) {
  const int px0 = blockIdx.x * 64;
  const int b = blockIdx.y;
  const int t = threadIdx.x;
  const int lane = t & 63, w = t >> 6;
  const int quad = lane >> 4, col = lane & 15;
  const int n0 = w * 80;
  const unsigned short* Abase = embb + ((size_t)b * PIX + px0) * 128;

  f32x4 acc[4][5];
#pragma unroll
  for (int mt = 0; mt < 4; ++mt)
#pragma unroll
    for (int nt = 0; nt < 5; ++nt) acc[mt][nt] = {0.f, 0.f, 0.f, 0.f};

#pragma unroll
  for (int ks = 0; ks < 4; ++ks) {
    bf16x8 bf[5], af[4];
#pragma unroll
    for (int nt = 0; nt < 5; ++nt)
      bf[nt] = *(const bf16x8*)(Rb + (size_t)(n0 + nt * 16 + col) * 128 +
                                ks * 32 + quad * 8);
#pragma unroll
    for (int mt = 0; mt < 4; ++mt)
      af[mt] = *(const bf16x8*)(Abase + (size_t)(mt * 16 + col) * 128 +
                                ks * 32 + quad * 8);
#pragma unroll
    for (int mt = 0; mt < 4; ++mt)
#pragma unroll
      for (int nt = 0; nt < 5; ++nt)
        acc[mt][nt] = __builtin_amdgcn_mfma_f32_16x16x32_bf16(
            af[mt], bf[nt], acc[mt][nt], 0, 0, 0);
  }

  const int j = lane & 3, kq = (lane >> 2) & 3;
#pragma unroll
  for (int mt = 0; mt < 4; ++mt) {
    const int px = px0 + mt * 16 + quad * 4 + j;
#pragma unroll
    for (int nt = 0; nt < 5; ++nt) {
      float v0 = acc[mt][nt][0], v1 = acc[mt][nt][1];
      float v2 = acc[mt][nt][2], v3 = acc[mt][nt][3];
      xpose4(v0, v1, v2, v3, lane);
      // lane now holds (dp, dn0, dn1, dn2) for (px, cls)
      const int gc = w * 20 + nt * 4 + kq;
      const float d2p = fmaxf(2.f - 2.f * v0, 0.f);
      const float dist = sqrtf(d2p);
      const float q0 = fmaxf(2.f - 2.f * v1, 0.f);
      const float q1 = fmaxf(2.f - 2.f * v2, 0.f);
      const float q2 = fmaxf(2.f - 2.f * v3, 0.f);
      const float dn0 = sqrtf(q0), dn1 = sqrtf(q1), dn2 = sqrtf(q2);
      const float pn = __expf(-2.f * fminf(q0, fminf(q1, q2)));
      const float pori = __expf(-2.f * d2p);
      const float minn = fminf(dn0, fminf(dn1, dn2));
      const float shifted = dist + 0.3f * fmaxf(2.0f - minn, 0.f);
      const float p = __expf(-2.f * shifted * shifted);
      const float clsv = __logf(fmaxf(p, 1e-5f) / fmaxf(1.f - p, 1e-5f));
      const size_t bc = ((size_t)b * NCLS + gc) * PIX + px;
      out[O0 + bc] = clsv;
      out[O1 + bc] = pn;
      out[O2 + bc] = dist;
      out[O4 + bc] = pori;
      const size_t b3 = (((size_t)b * NCLS + gc) * 3) * PIX + px;
      out[O3 + b3] = dn0;
      out[O3 + b3 + PIX] = dn1;
      out[O3 + b3 + 2 * PIX] = dn2;
    }
  }
}

// ---------------------------------------------------------------------------
extern "C" void kernel_launch(void* const* d_in, const int* in_sizes, int n_in,
                              void* d_out, int out_size, void* d_ws,
                              size_t ws_size, hipStream_t stream) {
  const float* x = (const float*)d_in[0];
  const float* w1 = (const float*)d_in[1];
  const float* c1b = (const float*)d_in[2];
  const float* g = (const float*)d_in[3];
  const float* be = (const float*)d_in[4];
  const float* mu = (const float*)d_in[5];
  const float* var = (const float*)d_in[6];
  const float* w2 = (const float*)d_in[7];
  const float* c2b = (const float*)d_in[8];
  const float* rw = (const float*)d_in[9];
  const float* rb = (const float*)d_in[10];
  const float* nw = (const float*)d_in[11];
  const float* nb = (const float*)d_in[12];
  float* out = (float*)d_out;

  unsigned short* xp = (unsigned short*)d_ws;   // bf16 padded NHWC input
  unsigned short* hp = xp + XP_ELEMS;           // bf16 padded NHWC hidden
  unsigned short* wt1 = hp + XP_ELEMS;          // 589,824 bf16
  unsigned short* wt2 = wt1 + 589824;           // 294,912 bf16
  float* bns = (float*)(wt2 + 294912);
  float* bno = bns + 256;
  float* rpv = bno + 256;                       // 10,240 fp32
  unsigned short* Rb = (unsigned short*)(rpv + 10240);  // 40,960 bf16
  unsigned short* embb = xp;                    // alias: xp dead after conv1

  hipMemsetAsync(xp, 0, XP_ELEMS * sizeof(unsigned short), stream);
  hipMemsetAsync(hp, 0, XP_ELEMS * sizeof(unsigned short), stream);
  pad_x_kernel<<<dim3(3, Hh, Bz), 256, 0, stream>>>(x, xp);
  prep_w_kernel<<<2304, 256, 0, stream>>>(w1, w2, c1b, g, be, mu, var, wt1, wt2,
                                          bns, bno);
  rep_norm_kernel<<<NCLS, 128, 0, stream>>>(rw, rb, rpv, Rb);
  mlp_neg_kernel<<<dim3(NCLS, 3), 128, 0, stream>>>(rpv, nw, nb, Rb);
  conv1_mfma<<<dim3(72, 2, Bz), 256, 0, stream>>>(xp, wt1, bns, bno, hp);
  conv2_mfma<<<dim3(72, 1, Bz), 256, 0, stream>>>(hp, wt2, c2b, nullptr, embb);
  score_mfma<<<dim3(144, Bz), 256, 0, stream>>>(embb, Rb, out);
}